// Round 11
// baseline (188.982 us; speedup 1.0000x reference)
//
#include <hip/hip_runtime.h>
#include <math.h>

#define BATCH 32
#define HQ 32
#define HKV 8
#define DHEAD 128
#define BS 16
#define MAXB 128
#define G 4
#define LMAX 2048
#define CHUNK 128
#define NCH (LMAX / CHUNK)        // 16 chunks per batch
#define NSLOT (BATCH * NCH)       // 512
#define NBKV (BATCH * HKV)        // 256
#define BLKF (BS * HKV * DHEAD)   // 16384 floats per cache block

#define SCALE_LOG2E 0.12752740305928724f  // (1/sqrt(128)) * log2(e)

typedef float v2f __attribute__((ext_vector_type(2)));

__device__ __forceinline__ v2f pk_fma(v2f a, v2f b, v2f c) {
    v2f d;
    asm("v_pk_fma_f32 %0, %1, %2, %3" : "=v"(d) : "v"(a), "v"(b), "v"(c));
    return d;
}
__device__ __forceinline__ v2f pk_mul(v2f a, v2f b) {
    v2f d;
    asm("v_pk_mul_f32 %0, %1, %2" : "=v"(d) : "v"(a), "v"(b));
    return d;
}
__device__ __forceinline__ float fexp2(float x) {
    float r;
    asm("v_exp_f32 %0, %1" : "=v"(r) : "v"(x));
    return r;
}

// one rotate-and-add step over each 16-lane row, 4 independent chains
#define ROR4(N, x0, x1, x2, x3)                                                   \
    asm("s_nop 1\n\t"                                                             \
        "v_add_f32_dpp %0, %0, %0 row_ror:" #N " row_mask:0xf bank_mask:0xf\n\t"  \
        "v_add_f32_dpp %1, %1, %1 row_ror:" #N " row_mask:0xf bank_mask:0xf\n\t"  \
        "v_add_f32_dpp %2, %2, %2 row_ror:" #N " row_mask:0xf bank_mask:0xf\n\t"  \
        "v_add_f32_dpp %3, %3, %3 row_ror:" #N " row_mask:0xf bank_mask:0xf"      \
        : "+v"(x0), "+v"(x1), "+v"(x2), "+v"(x3))

// ---------- prep: qs = RoPE(q) * scale * log2e  (layout [b][head][128]) ----------
__global__ __launch_bounds__(128) void paged_attn_prep(
    const float* __restrict__ query,
    const int*   __restrict__ context_lens,
    float* __restrict__ qs)
{
    const int bkv = blockIdx.x;
    const int kv  = bkv & 7;
    const int b   = bkv >> 3;
    const int tid = threadIdx.x;

    __shared__ float s_cos[64], s_sin[64];
    const int pos = context_lens[b];
    if (tid < 64) {
        float invf = exp2f((float)tid * -0.20762050593046014f); // 10000^(-t/64)
        float ang  = (float)pos * invf;
        s_cos[tid] = cosf(ang);
        s_sin[tid] = sinf(ang);
    }
    __syncthreads();

    for (int idx = tid; idx < G * DHEAD; idx += 128) {
        int h = idx >> 7, d = idx & 127;
        const float* qp = query + ((size_t)b * HQ + kv * G + h) * DHEAD;
        float x = qp[d], r;
        if (d < 64) r = x * s_cos[d]      - qp[d + 64] * s_sin[d];
        else        r = x * s_cos[d - 64] + qp[d - 64] * s_sin[d - 64];
        qs[(size_t)bkv * (G * DHEAD) + idx] = r * SCALE_LOG2E;
    }
}

// ---------- chunk: block = (b, 128 positions), all 8 kv fused ----------
// wave w: g = w>>1 owns positions [c0+32g, +32); half = w&1 owns kv half.
// Per position the wave reads a CONTIGUOUS 2KB of the 4KB row (two dense
// 1KB dwordx4 instructions); sibling wave reads the complementary 2KB.
__global__ __launch_bounds__(512) void paged_attn_chunk(
    const float* __restrict__ k_cache,
    const float* __restrict__ v_cache,
    const int*   __restrict__ block_table,
    const int*   __restrict__ context_lens,
    const float* __restrict__ qs,
    float*       __restrict__ wsacc,   // [NSLOT][HKV*G*DHEAD]
    float*       __restrict__ wsl)     // [NSLOT][HKV*G]
{
    const int c = blockIdx.x & (NCH - 1);
    const int b = blockIdx.x >> 4;
    const int pos = context_lens[b];
    const int c0  = c * CHUNK;
    if (c0 >= pos) return;             // position 'pos' handled in combine

    const int tid  = threadIdx.x;
    const int w    = tid >> 6;
    const int g    = w >> 1;           // position group (0..3)
    const int half = w & 1;            // kv half (0: kv0-3, 1: kv4-7)
    const int lane = tid & 63;
    const int l32  = lane & 31;
    const int hi   = lane >> 5;        // kv parity within an instruction slot

    __shared__ float s_acc[HKV][G][DHEAD];   // 16 KB
    __shared__ float s_l[HKV][G];

    // q fragments: slot i in {0,1} -> kv = half*4 + 2i + hi; d-slice 4*l32..+3
    v2f q2[2][G][2];
    #pragma unroll
    for (int i = 0; i < 2; ++i) {
        const int kv = half * 4 + 2 * i + hi;
        #pragma unroll
        for (int h = 0; h < G; ++h) {
            const float4 t4 = *(const float4*)
                &qs[(((size_t)b * HKV + kv) * G + h) * DHEAD + 4 * l32];
            q2[i][h][0] = v2f{t4.x, t4.y};
            q2[i][h][1] = v2f{t4.z, t4.w};
        }
    }

    v2f acc[2][G][2];
    float lsum[2][G];
    #pragma unroll
    for (int i = 0; i < 2; ++i)
        #pragma unroll
        for (int h = 0; h < G; ++h) {
            lsum[i][h] = 0.f;
            acc[i][h][0] = v2f{0.f, 0.f};
            acc[i][h][1] = v2f{0.f, 0.f};
        }

    const int pbase = c0 + g * 32;     // wave's first position
    if (pbase < pos) {                 // wave-uniform skip (no barrier inside)
        const int cbi = b * MAXB + (pbase >> 4);
        const int bt0 = __builtin_amdgcn_readfirstlane(block_table[cbi]);
        const int bt1 = __builtin_amdgcn_readfirstlane(block_table[cbi + 1]);

        // per-lane bases: slot0 floats [half*512 + 4*lane], slot1 = +256
        const int lofs = half * 512 + lane * 4;
        const float* kb0 = k_cache + (size_t)bt0 * BLKF + lofs;
        const float* kb1 = k_cache + (size_t)bt1 * BLKF + lofs;
        const float* vb0 = v_cache + (size_t)bt0 * BLKF + lofs;
        const float* vb1 = v_cache + (size_t)bt1 * BLKF + lofs;

#define LOADP(S, P)                                                            \
    do {                                                                       \
        const float* kb_ = (P) < 16 ? kb0 : kb1;                               \
        const float* vb_ = (P) < 16 ? vb0 : vb1;                               \
        const int o_ = ((P) & 15) * 1024;                                      \
        S[0] = *(const float4*)(kb_ + o_);        /* K slot0: 1KB dense  */    \
        S[1] = *(const float4*)(kb_ + o_ + 256);  /* K slot1: next 1KB   */    \
        S[2] = *(const float4*)(vb_ + o_);                                     \
        S[3] = *(const float4*)(vb_ + o_ + 256);                               \
    } while (0)

#define COMPP(S, P)                                                            \
    do {                                                                       \
        v2f kl0 = v2f{S[0].x, S[0].y}, kh0 = v2f{S[0].z, S[0].w};              \
        v2f kl1 = v2f{S[1].x, S[1].y}, kh1 = v2f{S[1].z, S[1].w};              \
        v2f e00 = pk_fma(q2[0][0][1], kh0, pk_mul(q2[0][0][0], kl0));          \
        v2f e01 = pk_fma(q2[0][1][1], kh0, pk_mul(q2[0][1][0], kl0));          \
        v2f e02 = pk_fma(q2[0][2][1], kh0, pk_mul(q2[0][2][0], kl0));          \
        v2f e03 = pk_fma(q2[0][3][1], kh0, pk_mul(q2[0][3][0], kl0));          \
        v2f e10 = pk_fma(q2[1][0][1], kh1, pk_mul(q2[1][0][0], kl1));          \
        v2f e11 = pk_fma(q2[1][1][1], kh1, pk_mul(q2[1][1][0], kl1));          \
        v2f e12 = pk_fma(q2[1][2][1], kh1, pk_mul(q2[1][2][0], kl1));          \
        v2f e13 = pk_fma(q2[1][3][1], kh1, pk_mul(q2[1][3][0], kl1));          \
        float d00 = e00.x + e00.y, d01 = e01.x + e01.y;                        \
        float d02 = e02.x + e02.y, d03 = e03.x + e03.y;                        \
        float d10 = e10.x + e10.y, d11 = e11.x + e11.y;                        \
        float d12 = e12.x + e12.y, d13 = e13.x + e13.y;                        \
        ROR4(8, d00, d01, d02, d03);  ROR4(8, d10, d11, d12, d13);             \
        ROR4(4, d00, d01, d02, d03);  ROR4(4, d10, d11, d12, d13);             \
        ROR4(2, d00, d01, d02, d03);  ROR4(2, d10, d11, d12, d13);             \
        ROR4(1, d00, d01, d02, d03);  ROR4(1, d10, d11, d12, d13);             \
        d00 += __shfl_xor(d00, 16, 64); d01 += __shfl_xor(d01, 16, 64);        \
        d02 += __shfl_xor(d02, 16, 64); d03 += __shfl_xor(d03, 16, 64);        \
        d10 += __shfl_xor(d10, 16, 64); d11 += __shfl_xor(d11, 16, 64);        \
        d12 += __shfl_xor(d12, 16, 64); d13 += __shfl_xor(d13, 16, 64);        \
        const bool act_ = (pbase + (P)) < pos;                                 \
        float w00 = act_ ? fexp2(d00) : 0.f;                                   \
        float w01 = act_ ? fexp2(d01) : 0.f;                                   \
        float w02 = act_ ? fexp2(d02) : 0.f;                                   \
        float w03 = act_ ? fexp2(d03) : 0.f;                                   \
        float w10 = act_ ? fexp2(d10) : 0.f;                                   \
        float w11 = act_ ? fexp2(d11) : 0.f;                                   \
        float w12 = act_ ? fexp2(d12) : 0.f;                                   \
        float w13 = act_ ? fexp2(d13) : 0.f;                                   \
        lsum[0][0] += w00; lsum[0][1] += w01;                                  \
        lsum[0][2] += w02; lsum[0][3] += w03;                                  \
        lsum[1][0] += w10; lsum[1][1] += w11;                                  \
        lsum[1][2] += w12; lsum[1][3] += w13;                                  \
        v2f ul0 = v2f{S[2].x, S[2].y}, uh0 = v2f{S[2].z, S[2].w};              \
        v2f ul1 = v2f{S[3].x, S[3].y}, uh1 = v2f{S[3].z, S[3].w};              \
        acc[0][0][0] = pk_fma(v2f{w00, w00}, ul0, acc[0][0][0]);               \
        acc[0][0][1] = pk_fma(v2f{w00, w00}, uh0, acc[0][0][1]);               \
        acc[0][1][0] = pk_fma(v2f{w01, w01}, ul0, acc[0][1][0]);               \
        acc[0][1][1] = pk_fma(v2f{w01, w01}, uh0, acc[0][1][1]);               \
        acc[0][2][0] = pk_fma(v2f{w02, w02}, ul0, acc[0][2][0]);               \
        acc[0][2][1] = pk_fma(v2f{w02, w02}, uh0, acc[0][2][1]);               \
        acc[0][3][0] = pk_fma(v2f{w03, w03}, ul0, acc[0][3][0]);               \
        acc[0][3][1] = pk_fma(v2f{w03, w03}, uh0, acc[0][3][1]);               \
        acc[1][0][0] = pk_fma(v2f{w10, w10}, ul1, acc[1][0][0]);               \
        acc[1][0][1] = pk_fma(v2f{w10, w10}, uh1, acc[1][0][1]);               \
        acc[1][1][0] = pk_fma(v2f{w11, w11}, ul1, acc[1][1][0]);               \
        acc[1][1][1] = pk_fma(v2f{w11, w11}, uh1, acc[1][1][1]);               \
        acc[1][2][0] = pk_fma(v2f{w12, w12}, ul1, acc[1][2][0]);               \
        acc[1][2][1] = pk_fma(v2f{w12, w12}, uh1, acc[1][2][1]);               \
        acc[1][3][0] = pk_fma(v2f{w13, w13}, ul1, acc[1][3][0]);               \
        acc[1][3][1] = pk_fma(v2f{w13, w13}, uh1, acc[1][3][1]);               \
    } while (0)

        float4 stA[4], stB[4];
        LOADP(stA, 0);
        #pragma unroll
        for (int p = 0; p < 32; p += 2) {
            LOADP(stB, p + 1);
            COMPP(stA, p);
            if (p + 2 < 32) LOADP(stA, p + 2);
            COMPP(stB, p + 1);
        }
#undef LOADP
#undef COMPP
    }

    // ---- epilogue: combine 4 g-waves per half via LDS add-rounds ----
    #pragma unroll
    for (int r = 0; r < 4; ++r) {
        if (g == r) {
            #pragma unroll
            for (int i = 0; i < 2; ++i) {
                const int kv = half * 4 + 2 * i + hi;
                float* dst = &s_acc[kv][0][0];
                #pragma unroll
                for (int h = 0; h < G; ++h) {
                    float* dp = dst + h * DHEAD + 4 * l32;
                    if (r == 0) {
                        dp[0] = acc[i][h][0].x; dp[1] = acc[i][h][0].y;
                        dp[2] = acc[i][h][1].x; dp[3] = acc[i][h][1].y;
                    } else {
                        dp[0] += acc[i][h][0].x; dp[1] += acc[i][h][0].y;
                        dp[2] += acc[i][h][1].x; dp[3] += acc[i][h][1].y;
                    }
                }
                if (l32 == 0) {
                    #pragma unroll
                    for (int h = 0; h < G; ++h) {
                        if (r == 0) s_l[kv][h]  = lsum[i][h];
                        else        s_l[kv][h] += lsum[i][h];
                    }
                }
            }
        }
        __syncthreads();
    }

    const size_t sbase = (size_t)blockIdx.x * (HKV * G * DHEAD);
    for (int idx = tid; idx < HKV * G * DHEAD; idx += 512)
        wsacc[sbase + idx] = (&s_acc[0][0][0])[idx];
    if (tid < HKV * G)
        wsl[(size_t)blockIdx.x * (HKV * G) + tid] = (&s_l[0][0])[tid];
}

// ---------- combine: chunk partials + new-token contribution ----------
__global__ __launch_bounds__(512) void paged_attn_combine(
    const float* __restrict__ query,
    const float* __restrict__ new_k,
    const float* __restrict__ new_v,
    const int*   __restrict__ context_lens,
    const float* __restrict__ wsacc,
    const float* __restrict__ wsl,
    float*       __restrict__ out)
{
    const int bkv = blockIdx.x;
    const int kv  = bkv & 7;
    const int b   = bkv >> 3;
    const int t   = threadIdx.x;
    const int h   = t >> 7;
    const int d   = t & 127;
    const int wv  = t >> 6;

    __shared__ float s_cos[64], s_sin[64], s_kn[DHEAD], s_ps[8];

    const int pos = context_lens[b];
    if (t < 64) {
        float invf = exp2f((float)t * -0.20762050593046014f);
        float ang  = (float)pos * invf;
        s_cos[t] = cosf(ang);
        s_sin[t] = sinf(ang);
    }
    __syncthreads();
    if (t < DHEAD) {
        const float* kp = new_k + ((size_t)b * HKV + kv) * DHEAD;
        float x = kp[t], r;
        if (t < 64) r = x * s_cos[t]      - kp[t + 64] * s_sin[t];
        else        r = x * s_cos[t - 64] + kp[t - 64] * s_sin[t - 64];
        s_kn[t] = r;
    }
    __syncthreads();

    float rq;
    {
        const float* qp = query + ((size_t)b * HQ + kv * G + h) * DHEAD;
        float x = qp[d];
        if (d < 64) rq = x * s_cos[d]      - qp[d + 64] * s_sin[d];
        else        rq = x * s_cos[d - 64] + qp[d - 64] * s_sin[d - 64];
        rq *= SCALE_LOG2E;
    }
    float part = rq * s_kn[d];
    #pragma unroll
    for (int off = 1; off < 64; off <<= 1) part += __shfl_xor(part, off, 64);
    if ((t & 63) == 0) s_ps[wv] = part;
    __syncthreads();

    const float wnew = fexp2(s_ps[2 * h] + s_ps[2 * h + 1]);

    const int ncc = (pos + CHUNK - 1) >> 7;   // chunks with positions < pos

    float asum = 0.f, lsum = 0.f;
    for (int cc = 0; cc < ncc; cc++) {
        const size_t slot = (size_t)b * NCH + cc;
        asum += wsacc[slot * (HKV * G * DHEAD) + kv * (G * DHEAD) + t];
        lsum += wsl[slot * (HKV * G) + kv * G + h];
    }
    const float vnew = new_v[((size_t)b * HKV + kv) * DHEAD + d];
    out[((size_t)b * HQ + kv * G + h) * DHEAD + d] =
        (asum + wnew * vnew) / (lsum + wnew);
}

extern "C" void kernel_launch(void* const* d_in, const int* in_sizes, int n_in,
                              void* d_out, int out_size, void* d_ws, size_t ws_size,
                              hipStream_t stream) {
    const float* query        = (const float*)d_in[0];
    const float* new_k        = (const float*)d_in[1];
    const float* new_v        = (const float*)d_in[2];
    const float* k_cache      = (const float*)d_in[3];
    const float* v_cache      = (const float*)d_in[4];
    const int*   block_table  = (const int*)d_in[5];
    const int*   context_lens = (const int*)d_in[6];
    float* out = (float*)d_out;

    float* wsacc = (float*)d_ws;                               // 512*4096 floats
    float* wsl   = wsacc + (size_t)NSLOT * HKV * G * DHEAD;    // 512*32
    float* qs    = wsl + (size_t)NSLOT * HKV * G;              // 256*512

    paged_attn_prep<<<dim3(NBKV), dim3(128), 0, stream>>>(
        query, context_lens, qs);
    paged_attn_chunk<<<dim3(NSLOT), dim3(512), 0, stream>>>(
        k_cache, v_cache, block_table, context_lens, qs, wsacc, wsl);
    paged_attn_combine<<<dim3(NBKV), dim3(512), 0, stream>>>(
        query, new_k, new_v, context_lens, wsacc, wsl, out);
}

// Round 15
// 71.486 us; speedup vs baseline: 2.6436x; 2.6436x over previous
//
#include <hip/hip_runtime.h>
#include <math.h>

#define BATCH 32
#define HQ 32
#define HKV 8
#define DHEAD 128
#define BS 16
#define MAXB 128
#define G 4              // HQ / HKV
#define CHUNK 256        // positions per chunk-block
#define MAXCH 8          // LMAX / CHUNK
#define NW 4             // waves per chunk block
#define NT (NW * 64)

#define NSLOT (BATCH * HKV * MAXCH)

typedef float v2f __attribute__((ext_vector_type(2)));

__device__ __forceinline__ v2f pk_fma(v2f a, v2f b, v2f c) {
    v2f d;
    asm("v_pk_fma_f32 %0, %1, %2, %3" : "=v"(d) : "v"(a), "v"(b), "v"(c));
    return d;
}
__device__ __forceinline__ v2f pk_mul(v2f a, v2f b) {
    v2f d;
    asm("v_pk_mul_f32 %0, %1, %2" : "=v"(d) : "v"(a), "v"(b));
    return d;
}

// rotate-and-add step over each 16-lane row for 4 independent chains.
#define ROR4(N, x0, x1, x2, x3)                                                   \
    asm("s_nop 1\n\t"                                                             \
        "v_add_f32_dpp %0, %0, %0 row_ror:" #N " row_mask:0xf bank_mask:0xf\n\t"  \
        "v_add_f32_dpp %1, %1, %1 row_ror:" #N " row_mask:0xf bank_mask:0xf\n\t"  \
        "v_add_f32_dpp %2, %2, %2 row_ror:" #N " row_mask:0xf bank_mask:0xf\n\t"  \
        "v_add_f32_dpp %3, %3, %3 row_ror:" #N " row_mask:0xf bank_mask:0xf"      \
        : "+v"(x0), "+v"(x1), "+v"(x2), "+v"(x3))

__global__ __launch_bounds__(NT) void paged_attn_chunk(
    const float* __restrict__ query,
    const float* __restrict__ new_k,
    const float* __restrict__ new_v,
    const float* __restrict__ k_cache,
    const float* __restrict__ v_cache,
    const int*   __restrict__ block_table,
    const int*   __restrict__ context_lens,
    float*       __restrict__ wsacc,       // [NSLOT][G*DHEAD]
    float*       __restrict__ wsl)         // [NSLOT][G]
{
    const int c   = blockIdx.x & (MAXCH - 1);
    const int bkv = blockIdx.x >> 3;
    const int kv  = bkv & 7;
    const int b   = bkv >> 3;

    const int pos = context_lens[b];
    const int len = pos + 1;
    const int c0  = c * CHUNK;
    if (c0 >= len) return;

    const int tid  = threadIdx.x;
    const int w    = tid >> 6;
    const int lane = tid & 63;
    const int grp  = lane >> 4;
    const int sub  = lane & 15;

    __shared__ float s_cos[64], s_sin[64];
    __shared__ float s_q[G][DHEAD];
    __shared__ float s_knew[DHEAD], s_vnew[DHEAD];
    __shared__ int   s_bt[CHUNK / BS];
    __shared__ float s_wacc[NW][G][DHEAD];
    __shared__ float s_wl[NW][G];

    // ---- RoPE tables (f32) ----
    if (tid < 64) {
        // inv_freq = 10000^(-tid/64) = exp2(-tid * log2(10000)/64)
        float invf = exp2f((float)tid * -0.20762050593046014f);
        float ang  = (float)pos * invf;
        s_cos[tid] = cosf(ang);
        s_sin[tid] = sinf(ang);
    }
    __syncthreads();

    const float scale = 0.08838834764831845f;  // 1/sqrt(128)

    for (int idx = tid; idx < G * DHEAD; idx += NT) {
        int h = idx >> 7, d = idx & 127;
        const float* qp = query + ((size_t)b * HQ + kv * G + h) * DHEAD;
        float x = qp[d], r;
        if (d < 64) r = x * s_cos[d]      - qp[d + 64] * s_sin[d];
        else        r = x * s_cos[d - 64] + qp[d - 64] * s_sin[d - 64];
        s_q[h][d] = r * scale;
    }
    if (tid < DHEAD) {
        int d = tid;
        const float* kp = new_k + ((size_t)b * HKV + kv) * DHEAD;
        float x = kp[d], r;
        if (d < 64) r = x * s_cos[d]      - kp[d + 64] * s_sin[d];
        else        r = x * s_cos[d - 64] + kp[d - 64] * s_sin[d - 64];
        s_knew[d] = r;
    } else if (tid < 2 * DHEAD) {
        int d = tid - DHEAD;
        s_vnew[d] = new_v[((size_t)b * HKV + kv) * DHEAD + d];
    }
    if (tid < CHUNK / BS) s_bt[tid] = block_table[b * MAXB + (c0 >> 4) + tid];
    __syncthreads();

    // per-lane q fragment: 8 dims as 4 float2, x 4 heads
    v2f q2[G][4];
    #pragma unroll
    for (int h = 0; h < G; h++)
        #pragma unroll
        for (int j = 0; j < 4; j++)
            q2[h][j] = v2f{s_q[h][sub * 8 + 2 * j], s_q[h][sub * 8 + 2 * j + 1]};

    v2f acc2[G][4];
    float l[G];
    #pragma unroll
    for (int h = 0; h < G; h++) {
        l[h] = 0.f;
        #pragma unroll
        for (int j = 0; j < 4; j++) acc2[h][j] = v2f{0.f, 0.f};
    }

    const size_t lofs = (size_t)kv * DHEAD + sub * 8;

    const int base = c0 + w * 64;
    int rem = len - base;
    int a = rem < 0 ? 0 : (rem > 64 ? 64 : rem);
    int nfull = a >> 2;
    int tail  = a & 3;

#define BODY(GUARDED)                                                          \
    {                                                                          \
        int slot = w * 64 + it * 4 + grp;                                      \
        int pi   = c0 + slot;                                                  \
        bool act = !(GUARDED) || (grp < tail);                                 \
        v2f k2[4], u2[4];                                                      \
        _Pragma("unroll")                                                      \
        for (int j = 0; j < 4; j++) { k2[j] = v2f{0.f, 0.f}; u2[j] = v2f{0.f, 0.f}; } \
        if (act) {                                                             \
            int blk = s_bt[slot >> 4];                                         \
            size_t row = (size_t)blk * (BS * HKV * DHEAD)                      \
                       + (size_t)(slot & 15) * (HKV * DHEAD) + lofs;           \
            float4 ka = *(const float4*)(k_cache + row);                       \
            float4 kb = *(const float4*)(k_cache + row + 4);                   \
            float4 va = *(const float4*)(v_cache + row);                       \
            float4 vb = *(const float4*)(v_cache + row + 4);                   \
            if (pi == pos) {                                                   \
                ka = *(const float4*)(s_knew + sub * 8);                       \
                kb = *(const float4*)(s_knew + sub * 8 + 4);                   \
                va = *(const float4*)(s_vnew + sub * 8);                       \
                vb = *(const float4*)(s_vnew + sub * 8 + 4);                   \
            }                                                                  \
            k2[0] = v2f{ka.x, ka.y}; k2[1] = v2f{ka.z, ka.w};                  \
            k2[2] = v2f{kb.x, kb.y}; k2[3] = v2f{kb.z, kb.w};                  \
            u2[0] = v2f{va.x, va.y}; u2[1] = v2f{va.z, va.w};                  \
            u2[2] = v2f{vb.x, vb.y}; u2[3] = v2f{vb.z, vb.w};                  \
        }                                                                      \
        float dt0, dt1, dt2, dt3;                                              \
        {                                                                      \
            v2f d0 = pk_fma(q2[0][3], k2[3], pk_fma(q2[0][2], k2[2],           \
                     pk_fma(q2[0][1], k2[1], pk_mul(q2[0][0], k2[0]))));       \
            v2f d1 = pk_fma(q2[1][3], k2[3], pk_fma(q2[1][2], k2[2],           \
                     pk_fma(q2[1][1], k2[1], pk_mul(q2[1][0], k2[0]))));       \
            v2f d2 = pk_fma(q2[2][3], k2[3], pk_fma(q2[2][2], k2[2],           \
                     pk_fma(q2[2][1], k2[1], pk_mul(q2[2][0], k2[0]))));       \
            v2f d3 = pk_fma(q2[3][3], k2[3], pk_fma(q2[3][2], k2[2],           \
                     pk_fma(q2[3][1], k2[1], pk_mul(q2[3][0], k2[0]))));       \
            dt0 = d0.x + d0.y; dt1 = d1.x + d1.y;                              \
            dt2 = d2.x + d2.y; dt3 = d3.x + d3.y;                              \
        }                                                                      \
        ROR4(8, dt0, dt1, dt2, dt3);                                           \
        ROR4(4, dt0, dt1, dt2, dt3);                                           \
        ROR4(2, dt0, dt1, dt2, dt3);                                           \
        ROR4(1, dt0, dt1, dt2, dt3);                                           \
        if (act) {                                                             \
            float wg0 = __expf(dt0), wg1 = __expf(dt1);                        \
            float wg2 = __expf(dt2), wg3 = __expf(dt3);                        \
            l[0] += wg0; l[1] += wg1; l[2] += wg2; l[3] += wg3;                \
            v2f w0 = v2f{wg0, wg0}, w1 = v2f{wg1, wg1};                        \
            v2f w2 = v2f{wg2, wg2}, w3 = v2f{wg3, wg3};                        \
            _Pragma("unroll")                                                  \
            for (int j = 0; j < 4; j++) {                                      \
                acc2[0][j] = pk_fma(w0, u2[j], acc2[0][j]);                    \
                acc2[1][j] = pk_fma(w1, u2[j], acc2[1][j]);                    \
                acc2[2][j] = pk_fma(w2, u2[j], acc2[2][j]);                    \
                acc2[3][j] = pk_fma(w3, u2[j], acc2[3][j]);                    \
            }                                                                  \
        }                                                                      \
    }

    #pragma unroll 2
    for (int it = 0; it < nfull; it++) BODY(false)
    if (tail) { int it = nfull; BODY(true) }
#undef BODY

    // ---- reduce across the 4 groups ----
    #pragma unroll
    for (int h = 0; h < G; h++) {
        l[h] += __shfl_xor(l[h], 16, 64);
        l[h] += __shfl_xor(l[h], 32, 64);
        #pragma unroll
        for (int j = 0; j < 4; j++) {
            float ax = acc2[h][j].x, ay = acc2[h][j].y;
            ax += __shfl_xor(ax, 16, 64); ax += __shfl_xor(ax, 32, 64);
            ay += __shfl_xor(ay, 16, 64); ay += __shfl_xor(ay, 32, 64);
            acc2[h][j] = v2f{ax, ay};
        }
    }
    if (lane < 16) {
        #pragma unroll
        for (int h = 0; h < G; h++)
            #pragma unroll
            for (int j = 0; j < 4; j++) {
                s_wacc[w][h][sub * 8 + 2 * j]     = acc2[h][j].x;
                s_wacc[w][h][sub * 8 + 2 * j + 1] = acc2[h][j].y;
            }
    }
    if (lane == 0) {
        #pragma unroll
        for (int h = 0; h < G; h++) s_wl[w][h] = l[h];
    }
    __syncthreads();

    const size_t slot_base = (size_t)blockIdx.x * (G * DHEAD);
    for (int idx = tid; idx < G * DHEAD; idx += NT) {
        float s = s_wacc[0][idx >> 7][idx & 127] + s_wacc[1][idx >> 7][idx & 127]
                + s_wacc[2][idx >> 7][idx & 127] + s_wacc[3][idx >> 7][idx & 127];
        wsacc[slot_base + idx] = s;
    }
    if (tid < G) {
        wsl[(size_t)blockIdx.x * G + tid] =
            s_wl[0][tid] + s_wl[1][tid] + s_wl[2][tid] + s_wl[3][tid];
    }
}

__global__ __launch_bounds__(512) void paged_attn_combine(
    const int*   __restrict__ context_lens,
    const float* __restrict__ wsacc,
    const float* __restrict__ wsl,
    float*       __restrict__ out)
{
    const int bkv = blockIdx.x;
    const int kv  = bkv & 7;
    const int b   = bkv >> 3;
    const int t   = threadIdx.x;
    const int h   = t >> 7;
    const int d   = t & 127;

    const int len = context_lens[b] + 1;
    const int nch = (len + CHUNK - 1) >> 8;

    float asum = 0.f, lsum = 0.f;
    for (int cc = 0; cc < nch; cc++) {
        asum += wsacc[((size_t)bkv * MAXCH + cc) * (G * DHEAD) + t];
        lsum += wsl[((size_t)bkv * MAXCH + cc) * G + h];
    }
    out[((size_t)b * HQ + kv * G + h) * DHEAD + d] = asum / lsum;
}

extern "C" void kernel_launch(void* const* d_in, const int* in_sizes, int n_in,
                              void* d_out, int out_size, void* d_ws, size_t ws_size,
                              hipStream_t stream) {
    const float* query        = (const float*)d_in[0];
    const float* new_k        = (const float*)d_in[1];
    const float* new_v        = (const float*)d_in[2];
    const float* k_cache      = (const float*)d_in[3];
    const float* v_cache      = (const float*)d_in[4];
    const int*   block_table  = (const int*)d_in[5];
    const int*   context_lens = (const int*)d_in[6];
    float* out = (float*)d_out;

    float* wsacc = (float*)d_ws;
    float* wsl   = wsacc + (size_t)NSLOT * G * DHEAD;

    paged_attn_chunk<<<dim3(BATCH * HKV * MAXCH), dim3(NT), 0, stream>>>(
        query, new_k, new_v, k_cache, v_cache, block_table, context_lens,
        wsacc, wsl);
    paged_attn_combine<<<dim3(BATCH * HKV), dim3(512), 0, stream>>>(
        context_lens, wsacc, wsl, out);
}